// Round 1
// baseline (53.342 us; speedup 1.0000x reference)
//
#include <hip/hip_runtime.h>
#include <math.h>

// combined = hidden_states (identity experts + normalized weights sum to 1)
__global__ void moe_copy_kernel(const float4* __restrict__ in,
                                float4* __restrict__ out, int n4) {
    int i = blockIdx.x * blockDim.x + threadIdx.x;
    int stride = gridDim.x * blockDim.x;
    for (; i < n4; i += stride) {
        out[i] = in[i];
    }
}

// One 64-lane wave per token row; lane e holds logit for expert e (E=64).
// Butterfly argmax with tie-break to smaller index (matches jax.lax.top_k),
// then second max excluding the winner. Weights: softmax over the top-2
// logits (global softmax denominator cancels under normalization).
__global__ void moe_router_kernel(const float* __restrict__ logits,
                                  float* __restrict__ out_idx,
                                  float* __restrict__ out_w, int N) {
    int gtid = blockIdx.x * blockDim.x + threadIdx.x;
    int row = gtid >> 6;
    int lane = threadIdx.x & 63;
    if (row >= N) return;

    float v = logits[row * 64 + lane];

    // top-1 (value, index) butterfly reduce
    float bv = v; int bi = lane;
    #pragma unroll
    for (int off = 32; off >= 1; off >>= 1) {
        float ov = __shfl_xor(bv, off);
        int   oi = __shfl_xor(bi, off);
        if (ov > bv || (ov == bv && oi < bi)) { bv = ov; bi = oi; }
    }
    // top-2: mask out the winner lane, reduce again
    float sv = (lane == bi) ? -INFINITY : v;
    int si = lane;
    #pragma unroll
    for (int off = 32; off >= 1; off >>= 1) {
        float ov = __shfl_xor(sv, off);
        int   oi = __shfl_xor(si, off);
        if (ov > sv || (ov == sv && oi < si)) { sv = ov; si = oi; }
    }

    if (lane == 0) {
        float e  = expf(sv - bv);          // <= 1
        float w0 = 1.0f / (1.0f + e);
        float w1 = e / (1.0f + e);
        out_idx[row * 2 + 0] = (float)bi;
        out_idx[row * 2 + 1] = (float)si;
        out_w[row * 2 + 0]   = w0;
        out_w[row * 2 + 1]   = w1;
    }
}

extern "C" void kernel_launch(void* const* d_in, const int* in_sizes, int n_in,
                              void* d_out, int out_size, void* d_ws, size_t ws_size,
                              hipStream_t stream) {
    const float* hidden = (const float*)d_in[0];   // [N, H] f32
    const float* router = (const float*)d_in[1];   // [N, E] f32 logits
    // top_k (d_in[2]) is fixed at 2 for this problem instance.

    const int N = 8192, H = 4096;
    const long long combined_elems = (long long)N * H;       // 33,554,432

    float* out_combined = (float*)d_out;
    float* out_idx      = out_combined + combined_elems;     // [N, 2] as f32
    float* out_w        = out_idx + (long long)N * 2;        // [N, 2] f32

    // (a) combined = hidden_states, vectorized float4 copy
    int n4 = (int)(combined_elems / 4);
    moe_copy_kernel<<<2048, 256, 0, stream>>>(
        (const float4*)hidden, (float4*)out_combined, n4);

    // (b) router: one wave per row, 4 waves per block
    int waves_per_block = 256 / 64;
    int blocks = (N + waves_per_block - 1) / waves_per_block;
    moe_router_kernel<<<blocks, 256, 0, stream>>>(router, out_idx, out_w, N);
}

// Round 3
// 48.098 us; speedup vs baseline: 1.1090x; 1.1090x over previous
//
#include <hip/hip_runtime.h>
#include <math.h>

// Native clang vector type — accepted by __builtin_nontemporal_store
// (HIP's float4 class is not).
typedef float f4 __attribute__((ext_vector_type(4)));

// Fused MoE dispatch-collapse kernel.
//   combined = hidden_states  (identity experts; normalized weights sum to 1)
//   expert_indices / routing_weights from top-2 of the logits (E=64).
//
// Grid: 2048 blocks x 256 threads. Each block's 4 waves each own one router
// row (8192 rows / 2048 blocks = 4), then all threads run the fixed-trip
// grid-stride f4 copy with nontemporal stores.
__global__ __launch_bounds__(256) void moe_fused_kernel(
    const f4* __restrict__ in, f4* __restrict__ out, int n4,
    const float* __restrict__ logits, float* __restrict__ out_idx,
    float* __restrict__ out_w, int N) {
    const int lane = threadIdx.x & 63;
    const int wave = threadIdx.x >> 6;          // 0..3
    const int row  = blockIdx.x * 4 + wave;     // one router row per wave

    // ---- router: top-2 of 64 logits, one lane per expert ----
    if (row < N) {
        float v = logits[row * 64 + lane];

        float bv = v; int bi = lane;
        #pragma unroll
        for (int off = 32; off >= 1; off >>= 1) {
            float ov = __shfl_xor(bv, off);
            int   oi = __shfl_xor(bi, off);
            if (ov > bv || (ov == bv && oi < bi)) { bv = ov; bi = oi; }
        }
        float sv = (lane == bi) ? -INFINITY : v;
        int si = lane;
        #pragma unroll
        for (int off = 32; off >= 1; off >>= 1) {
            float ov = __shfl_xor(sv, off);
            int   oi = __shfl_xor(si, off);
            if (ov > sv || (ov == sv && oi < si)) { sv = ov; si = oi; }
        }
        if (lane == 0) {
            float e  = expf(sv - bv);           // <= 1
            float w0 = 1.0f / (1.0f + e);
            out_idx[row * 2 + 0] = (float)bi;
            out_idx[row * 2 + 1] = (float)si;
            out_w[row * 2 + 0]   = w0;
            out_w[row * 2 + 1]   = e * w0;
        }
    }

    // ---- copy: 16 fixed iterations, 4 loads in flight, NT stores ----
    const int stride = gridDim.x * blockDim.x;       // 524288
    int i = blockIdx.x * blockDim.x + threadIdx.x;
    #pragma unroll 4
    for (int it = 0; it < 16; ++it) {
        if (i < n4) {
            f4 v = in[i];
            __builtin_nontemporal_store(v, &out[i]);
        }
        i += stride;
    }
}

extern "C" void kernel_launch(void* const* d_in, const int* in_sizes, int n_in,
                              void* d_out, int out_size, void* d_ws, size_t ws_size,
                              hipStream_t stream) {
    const float* hidden = (const float*)d_in[0];   // [N, H] f32
    const float* router = (const float*)d_in[1];   // [N, E] f32 logits

    const int N = 8192, H = 4096;
    const long long combined_elems = (long long)N * H;   // 33,554,432

    float* out_combined = (float*)d_out;
    float* out_idx      = out_combined + combined_elems; // [N, 2] as f32
    float* out_w        = out_idx + (long long)N * 2;    // [N, 2] f32

    int n4 = (int)(combined_elems / 4);                  // 8,388,608
    moe_fused_kernel<<<2048, 256, 0, stream>>>(
        (const f4*)hidden, (f4*)out_combined, n4,
        router, out_idx, out_w, N);
}